// Round 3
// baseline (430.653 us; speedup 1.0000x reference)
//
#include <hip/hip_runtime.h>

typedef unsigned short u16;
typedef unsigned int   u32;

#define HID   128
#define HEADS 4
#define CH    128
#define HC    512
#define UT    32   // nodes per block in the update GEMM

typedef __bf16 bf16x8v __attribute__((ext_vector_type(8)));
typedef float  f32x4v  __attribute__((ext_vector_type(4)));
union FragU { uint4 u; bf16x8v b; };

// bf16 pack/unpack for INTERNAL workspace tensors only (inputs/outputs f32)
static __device__ __forceinline__ float bf2f(u16 u) {
  union { u32 u; float f; } x;
  x.u = ((u32)u) << 16;
  return x.f;
}
static __device__ __forceinline__ u16 f2bf(float f) {
  union { float f; u32 u; } x;
  x.f = f;
  u32 r = x.u + 0x7fffu + ((x.u >> 16) & 1u);
  return (u16)(r >> 16);
}

static __device__ __forceinline__ void unpack8(uint4 raw, float* dst) {
  dst[0] = bf2f((u16)(raw.x & 0xffffu));
  dst[1] = bf2f((u16)(raw.x >> 16));
  dst[2] = bf2f((u16)(raw.y & 0xffffu));
  dst[3] = bf2f((u16)(raw.y >> 16));
  dst[4] = bf2f((u16)(raw.z & 0xffffu));
  dst[5] = bf2f((u16)(raw.z >> 16));
  dst[6] = bf2f((u16)(raw.w & 0xffffu));
  dst[7] = bf2f((u16)(raw.w >> 16));
}

// ---------------- CSR: histogram ----------------
__global__ void hist_kernel(const int* dst_idx, int* deg, int E) {
  int e = blockIdx.x * 256 + threadIdx.x;
  if (e < E) atomicAdd(&deg[dst_idx[e]], 1);
}

// ---------------- CSR scan phase 1: per-block sums ----------------
__global__ void blocksum_kernel(const int* deg, int* bsums, int n) {
  __shared__ int buf[256];
  int i = blockIdx.x * 256 + threadIdx.x;
  int v = 0;
  if (i < n) v = deg[i];
  buf[threadIdx.x] = v;
  __syncthreads();
  for (int off = 128; off > 0; off >>= 1) {
    if (threadIdx.x < off) buf[threadIdx.x] += buf[threadIdx.x + off];
    __syncthreads();
  }
  if (threadIdx.x == 0) bsums[blockIdx.x] = buf[0];
}

// ---------------- CSR scan phase 2: exclusive scan of block sums ------------
__global__ void scanb_kernel(const int* bsums, int* boffs, int nb) {
  __shared__ int buf[256];
  __shared__ int carry_s;
  int tid = threadIdx.x;
  if (tid == 0) carry_s = 0;
  __syncthreads();
  for (int base = 0; base < nb; base += 256) {
    int i = base + tid;
    int v = 0;
    if (i < nb) v = bsums[i];
    buf[tid] = v;
    __syncthreads();
    for (int off = 1; off < 256; off <<= 1) {
      int t = 0;
      if (tid >= off) t = buf[tid - off];
      __syncthreads();
      buf[tid] += t;
      __syncthreads();
    }
    int incl = buf[tid] + carry_s;
    if (i < nb) boffs[i] = incl - v;
    __syncthreads();
    if (tid == 255) carry_s = incl;
    __syncthreads();
  }
}

// ---------------- CSR scan phase 3: in-block scan + block offset ------------
__global__ void scanfinal_kernel(const int* deg, const int* boffs,
                                 int* row_ptr, int* cursor, int n) {
  __shared__ int buf[256];
  int tid = threadIdx.x;
  int i = blockIdx.x * 256 + tid;
  int v = 0;
  if (i < n) v = deg[i];
  buf[tid] = v;
  __syncthreads();
  for (int off = 1; off < 256; off <<= 1) {
    int t = 0;
    if (tid >= off) t = buf[tid - off];
    __syncthreads();
    buf[tid] += t;
    __syncthreads();
  }
  int incl = buf[tid] + boffs[blockIdx.x];
  if (i < n) {
    row_ptr[i + 1] = incl;
    cursor[i] = incl - v;
  }
  if (i == 0) row_ptr[0] = 0;
}

// ---------------- CSR: scatter ----------------
__global__ void scatter_kernel(const int* src_idx, const int* dst_idx,
                               int* cursor, int* col, int E) {
  int e = blockIdx.x * 256 + threadIdx.x;
  if (e < E) {
    int pos = atomicAdd(&cursor[dst_idx[e]], 1);
    col[pos] = src_idx[e];
  }
}

// ---- pack h_X into MFMA A-fragment order (bf16) ----
__global__ void packH_kernel(const float* __restrict__ hX,
                             u16* __restrict__ hpack, int N, int total) {
  int i = blockIdx.x * 256 + threadIdx.x;
  if (i >= total) return;
  int j = i & 7;
  int lane = (i >> 3) & 63;
  int kc = (i >> 9) & 3;
  int ntile = i >> 11;
  int node = ntile * 16 + (lane & 15);
  int k = kc * 32 + (lane >> 4) * 8 + j;
  float v = (node < N) ? hX[(size_t)node * HID + k] : 0.f;
  hpack[i] = f2bf(v);
}

// ---- pack [Wq|Wk|Wv|Wskip] (1664 cols) into B-fragment order (bf16) ----
__global__ void packW4_kernel(const float* __restrict__ Wq,
                              const float* __restrict__ Wk,
                              const float* __restrict__ Wv,
                              const float* __restrict__ Wsk,
                              u16* __restrict__ Wp, int total) {
  int i = blockIdx.x * 256 + threadIdx.x;
  if (i >= total) return;
  int j = i & 7;
  int lane = (i >> 3) & 63;
  int kc = (i >> 9) & 3;
  int ct = i >> 11;
  int n = ct * 16 + (lane & 15);
  int k = kc * 32 + (lane >> 4) * 8 + j;
  float w;
  if (n < 512) w = Wq[(size_t)k * HC + n];
  else if (n < 1024) w = Wk[(size_t)k * HC + (n - 512)];
  else if (n < 1536) w = Wv[(size_t)k * HC + (n - 1024)];
  else w = Wsk[(size_t)k * HID + (n - 1536)];
  Wp[i] = f2bf(w);
}

// ---- MFMA projection v3: LDS-free, B-in-registers, M-chunked ----
// Each wave owns 2 col-tiles (B frags in 32 VGPR, loaded once from L2-hot Wp)
// and loops over 8 M-tiles: 4 coalesced A-frag loads + 8 MFMA + wave-wide
// stores per m-tile. No LDS, no barriers -> high occupancy, TLP hides all
// latency. 2x m-tile unroll keeps 8 loads in flight per wave.
__global__ __launch_bounds__(256) void mfma_proj_kernel(
    const u16* __restrict__ hpack, const u16* __restrict__ Wp,
    const float* __restrict__ bq, const float* __restrict__ bk,
    const float* __restrict__ bv, const float* __restrict__ bsk,
    u16* __restrict__ qb, u16* __restrict__ kbuf, u16* __restrict__ vbuf,
    float* __restrict__ skipf, int N) {
  int t = threadIdx.x;
  int wv = t >> 6;
  int L = t & 63;
  int bx = blockIdx.x;        // 0..12 : block covers 8 col-tiles, wave 2
  int my0 = blockIdx.y * 8;   // 8 m-tiles (128 nodes) per block

  // ---- B fragments: 2 col-tiles x 4 kc, loaded once (L2-resident) ----
  FragU Bf[2][4];
  const u16* wb0 = Wp + (size_t)(bx * 8 + wv * 2) * 2048;
#pragma unroll
  for (int cc = 0; cc < 2; ++cc)
#pragma unroll
    for (int kc = 0; kc < 4; ++kc)
      Bf[cc][kc].u = *(const uint4*)(wb0 + cc * 2048 + kc * 512 + L * 8);

  // ---- per-cc output routing (wave-uniform) + per-lane bias ----
  int colq = L & 15;
  int quad = L >> 4;
  u16* outB_[2];
  float bval[2];
  int nl_[2];
  int isF32_[2];
#pragma unroll
  for (int cc = 0; cc < 2; ++cc) {
    int n = (bx * 8 + wv * 2 + cc) * 16 + colq;
    const float* bias;
    if (n < 512) {
      outB_[cc] = qb; bias = bq; nl_[cc] = n; isF32_[cc] = 0;
    } else if (n < 1024) {
      outB_[cc] = kbuf; bias = bk; nl_[cc] = n - 512; isF32_[cc] = 0;
    } else if (n < 1536) {
      outB_[cc] = vbuf; bias = bv; nl_[cc] = n - 1024; isF32_[cc] = 0;
    } else {
      outB_[cc] = (u16*)skipf; bias = bsk; nl_[cc] = n - 1536; isF32_[cc] = 1;
    }
    bval[cc] = bias[nl_[cc]];
  }

  const u16* ha = hpack + (size_t)my0 * 2048;

  for (int mt = 0; mt < 8; mt += 2) {
    // issue all 8 A-fragment loads before any MFMA
    FragU a0[4], a1[4];
#pragma unroll
    for (int kc = 0; kc < 4; ++kc) {
      a0[kc].u = *(const uint4*)(ha + (size_t)mt * 2048 + kc * 512 + L * 8);
      a1[kc].u =
          *(const uint4*)(ha + (size_t)(mt + 1) * 2048 + kc * 512 + L * 8);
    }

    f32x4v ac00 = (f32x4v){0.f, 0.f, 0.f, 0.f};
    f32x4v ac01 = (f32x4v){0.f, 0.f, 0.f, 0.f};
    f32x4v ac10 = (f32x4v){0.f, 0.f, 0.f, 0.f};
    f32x4v ac11 = (f32x4v){0.f, 0.f, 0.f, 0.f};
#pragma unroll
    for (int kc = 0; kc < 4; ++kc) {
      ac00 = __builtin_amdgcn_mfma_f32_16x16x32_bf16(a0[kc].b, Bf[0][kc].b,
                                                     ac00, 0, 0, 0);
      ac01 = __builtin_amdgcn_mfma_f32_16x16x32_bf16(a0[kc].b, Bf[1][kc].b,
                                                     ac01, 0, 0, 0);
      ac10 = __builtin_amdgcn_mfma_f32_16x16x32_bf16(a1[kc].b, Bf[0][kc].b,
                                                     ac10, 0, 0, 0);
      ac11 = __builtin_amdgcn_mfma_f32_16x16x32_bf16(a1[kc].b, Bf[1][kc].b,
                                                     ac11, 0, 0, 0);
    }

    // epilogue: bias + convert + store (wave-uniform branch per cc)
#pragma unroll
    for (int half = 0; half < 2; ++half) {
      int nodeBase = (my0 + mt + half) * 16 + quad * 4;
#pragma unroll
      for (int cc = 0; cc < 2; ++cc) {
        const f32x4v& a =
            half ? (cc ? ac11 : ac10) : (cc ? ac01 : ac00);
        if (isF32_[cc]) {
#pragma unroll
          for (int rg = 0; rg < 4; ++rg) {
            int node = nodeBase + rg;
            if (node < N)
              skipf[(size_t)node * HID + nl_[cc]] = a[rg] + bval[cc];
          }
        } else {
          u16* ob = outB_[cc];
#pragma unroll
          for (int rg = 0; rg < 4; ++rg) {
            int node = nodeBase + rg;
            if (node < N)
              ob[(size_t)node * HC + nl_[cc]] = f2bf(a[rg] + bval[cc]);
          }
        }
      }
    }
  }
}

// ---- FUSED per-node attention: software-pipelined 4-edge groups ----
// Depth-1 prefetch: group g+1's col_src + 8 k/v gathers are issued BEFORE
// group g's compute, so the compute's s_waitcnt drains only group-g loads
// (8 prefetch loads stay in flight across the compute). For the typical
// deg-8 node (2 groups) the second group's gather latency is fully hidden.
// The out-row RMW read is hoisted to kernel entry to hide tail latency.
__global__ void fused_attn_kernel(const u16* __restrict__ qb,
                                  const u16* __restrict__ kb,
                                  const u16* __restrict__ vb,
                                  const int* __restrict__ row_ptr,
                                  const int* __restrict__ col_src,
                                  float* out, int N) {
  int node = blockIdx.x * 4 + (threadIdx.x >> 6);
  if (node >= N) return;
  int lane = threadIdx.x & 63;
  int head = lane >> 4;
  int r = lane & 15;
  int foff = head * CH + r * 8;
  const float sscale = 0.08838834764831845f;  // 1/sqrt(128)

  float qf[8];
  unpack8(*(const uint4*)(qb + (size_t)node * HC + foff), qf);

  // hoisted RMW read of the skip row (written earlier by mfma_proj)
  float* orow = out + (size_t)node * HID + r * 8;
  float4 oa = {0.f, 0.f, 0.f, 0.f};
  float4 obv = {0.f, 0.f, 0.f, 0.f};
  if (head == 0) {
    oa = *(const float4*)(orow);
    obv = *(const float4*)(orow + 4);
  }

  float m = -3.402823466e38f;
  float l = 0.f;
  float acc[8];
#pragma unroll
  for (int j = 0; j < 8; ++j) acc[j] = 0.f;

  int e0 = row_ptr[node];
  int e1 = row_ptr[node + 1];
  int nfull = (e1 - e0) >> 2;

  uint4 ck[4], cv[4];
  if (nfull > 0) {
    int s0 = col_src[e0];
    int s1 = col_src[e0 + 1];
    int s2 = col_src[e0 + 2];
    int s3 = col_src[e0 + 3];
    ck[0] = *(const uint4*)(kb + (size_t)s0 * HC + foff);
    ck[1] = *(const uint4*)(kb + (size_t)s1 * HC + foff);
    ck[2] = *(const uint4*)(kb + (size_t)s2 * HC + foff);
    ck[3] = *(const uint4*)(kb + (size_t)s3 * HC + foff);
    cv[0] = *(const uint4*)(vb + (size_t)s0 * HC + foff);
    cv[1] = *(const uint4*)(vb + (size_t)s1 * HC + foff);
    cv[2] = *(const uint4*)(vb + (size_t)s2 * HC + foff);
    cv[3] = *(const uint4*)(vb + (size_t)s3 * HC + foff);
  }

  for (int g = 0; g < nfull; ++g) {
    // ---- prefetch group g+1 (issued before the g-compute's waitcnt) ----
    uint4 nk[4], nv[4];
    int hasNext = (g + 1 < nfull);
    if (hasNext) {
      int nb = e0 + (g + 1) * 4;
      int s0 = col_src[nb];
      int s1 = col_src[nb + 1];
      int s2 = col_src[nb + 2];
      int s3 = col_src[nb + 3];
      nk[0] = *(const uint4*)(kb + (size_t)s0 * HC + foff);
      nk[1] = *(const uint4*)(kb + (size_t)s1 * HC + foff);
      nk[2] = *(const uint4*)(kb + (size_t)s2 * HC + foff);
      nk[3] = *(const uint4*)(kb + (size_t)s3 * HC + foff);
      nv[0] = *(const uint4*)(vb + (size_t)s0 * HC + foff);
      nv[1] = *(const uint4*)(vb + (size_t)s1 * HC + foff);
      nv[2] = *(const uint4*)(vb + (size_t)s2 * HC + foff);
      nv[3] = *(const uint4*)(vb + (size_t)s3 * HC + foff);
    }

    // ---- compute on current group ----
    float kf0[8], kf1[8], kf2[8], kf3[8];
    unpack8(ck[0], kf0);
    unpack8(ck[1], kf1);
    unpack8(ck[2], kf2);
    unpack8(ck[3], kf3);
    float p0 = 0.f, p1 = 0.f, p2 = 0.f, p3 = 0.f;
#pragma unroll
    for (int j = 0; j < 8; ++j) {
      p0 = fmaf(kf0[j], qf[j], p0);
      p1 = fmaf(kf1[j], qf[j], p1);
      p2 = fmaf(kf2[j], qf[j], p2);
      p3 = fmaf(kf3[j], qf[j], p3);
    }
    p0 += __shfl_xor(p0, 1);
    p1 += __shfl_xor(p1, 1);
    p2 += __shfl_xor(p2, 1);
    p3 += __shfl_xor(p3, 1);
    p0 += __shfl_xor(p0, 2);
    p1 += __shfl_xor(p1, 2);
    p2 += __shfl_xor(p2, 2);
    p3 += __shfl_xor(p3, 2);
    p0 += __shfl_xor(p0, 4);
    p1 += __shfl_xor(p1, 4);
    p2 += __shfl_xor(p2, 4);
    p3 += __shfl_xor(p3, 4);
    p0 += __shfl_xor(p0, 8);
    p1 += __shfl_xor(p1, 8);
    p2 += __shfl_xor(p2, 8);
    p3 += __shfl_xor(p3, 8);
    float sc0 = p0 * sscale;
    float sc1 = p1 * sscale;
    float sc2 = p2 * sscale;
    float sc3 = p3 * sscale;
    float mnew = fmaxf(fmaxf(m, fmaxf(sc0, sc1)), fmaxf(sc2, sc3));
    float so = __expf(m - mnew);
    float pe0 = __expf(sc0 - mnew);
    float pe1 = __expf(sc1 - mnew);
    float pe2 = __expf(sc2 - mnew);
    float pe3 = __expf(sc3 - mnew);
    l = l * so + (pe0 + pe1) + (pe2 + pe3);
    float vf0[8], vf1[8], vf2[8], vf3[8];
    unpack8(cv[0], vf0);
    unpack8(cv[1], vf1);
    unpack8(cv[2], vf2);
    unpack8(cv[3], vf3);
#pragma unroll
    for (int j = 0; j < 8; ++j) {
      float add = fmaf(pe0, vf0[j],
                       fmaf(pe1, vf1[j], fmaf(pe2, vf2[j], pe3 * vf3[j])));
      acc[j] = fmaf(acc[j], so, add);
    }
    m = mnew;

    if (hasNext) {
#pragma unroll
      for (int j = 0; j < 4; ++j) {
        ck[j] = nk[j];
        cv[j] = nv[j];
      }
    }
  }

  for (int e = e0 + nfull * 4; e < e1; ++e) {  // tail: 0-3 edges
    int s0 = col_src[e];
    uint4 k0 = *(const uint4*)(kb + (size_t)s0 * HC + foff);
    uint4 v0 = *(const uint4*)(vb + (size_t)s0 * HC + foff);
    float kf0[8];
    unpack8(k0, kf0);
    float p0 = 0.f;
#pragma unroll
    for (int j = 0; j < 8; ++j) p0 = fmaf(kf0[j], qf[j], p0);
    p0 += __shfl_xor(p0, 1);
    p0 += __shfl_xor(p0, 2);
    p0 += __shfl_xor(p0, 4);
    p0 += __shfl_xor(p0, 8);
    float sc0 = p0 * sscale;
    float mnew = fmaxf(m, sc0);
    float so = __expf(m - mnew);
    float pe0 = __expf(sc0 - mnew);
    l = l * so + pe0;
    float vf0[8];
    unpack8(v0, vf0);
#pragma unroll
    for (int j = 0; j < 8; ++j) acc[j] = fmaf(acc[j], so, pe0 * vf0[j]);
    m = mnew;
  }

  float inv = 0.f;
  if (l > 0.f) inv = 1.0f / l;
  float val[8];
#pragma unroll
  for (int j = 0; j < 8; ++j) {
    float x = acc[j] * inv;
    x += __shfl_xor(x, 16);
    x += __shfl_xor(x, 32);
    val[j] = x * 0.25f;  // mean over 4 heads
  }

  if (head == 0) {
    oa.x += val[0];
    oa.y += val[1];
    oa.z += val[2];
    oa.w += val[3];
    obv.x += val[4];
    obv.y += val[5];
    obv.z += val[6];
    obv.w += val[7];
    *(float4*)(orow) = oa;
    *(float4*)(orow + 4) = obv;
  }
}

// ---------------- cvec = h_t @ Wup[128:256] + bup (all f32) ----------------
// parallelized: 4 k-chunks x 128 cols (one block, 512 threads)
__global__ void cvec_kernel(const float* h_t, const float* Wup,
                            const float* bup, float* cvec) {
  __shared__ float part[4][128];
  int c = threadIdx.x & 127;
  int kc = threadIdx.x >> 7;
  float acc = 0.f;
  for (int k = kc * 32; k < kc * 32 + 32; ++k)
    acc = fmaf(h_t[k], Wup[(size_t)(128 + k) * 128 + c], acc);
  part[kc][c] = acc;
  __syncthreads();
  if (kc == 0)
    cvec[c] = part[0][c] + part[1][c] + part[2][c] + part[3][c] + bup[c];
}

// ------- update GEMM + relu + LayerNorm, in-place on d_out (f32) -------
__global__ __launch_bounds__(256) void ATTLayer_19396072308956_kernel(
    float* out, const float* __restrict__ Wup, const float* __restrict__ cvec,
    const float* __restrict__ gamma, const float* __restrict__ beta, int N) {
  __shared__ float Wl[64 * 128];
  __shared__ float Hl[UT * 128];
  int t = threadIdx.x;
  int n0 = blockIdx.x * UT;

  for (int i = t * 4; i < UT * 128; i += 1024) {
    int node = n0 + (i >> 7);
    float4 v;
    if (node < N) {
      v = *(const float4*)(out + (size_t)node * HID + (i & 127));
    } else {
      v.x = 0.f; v.y = 0.f; v.z = 0.f; v.w = 0.f;
    }
    *(float4*)(Hl + i) = v;
  }

  int wv = t >> 6;
  int r = t & 63;
  int c0 = 2 * r;
  float2 cv = *(const float2*)(cvec + c0);
  float a0[8];
  float a1[8];
  for (int j = 0; j < 8; ++j) {
    a0[j] = cv.x;
    a1[j] = cv.y;
  }

  for (int ph = 0; ph < 2; ++ph) {
    __syncthreads();
    for (int i = t * 4; i < 64 * 128; i += 1024) {
      *(float4*)(Wl + i) = *(const float4*)(Wup + (size_t)ph * 64 * 128 + i);
    }
    __syncthreads();
    const float* hbase = Hl + (wv * 8) * 128 + ph * 64;
#pragma unroll 8
    for (int k = 0; k < 64; ++k) {
      float2 w2 = *(const float2*)(Wl + k * 128 + c0);
      for (int j = 0; j < 8; ++j) {
        float h = hbase[j * 128 + k];
        a0[j] = fmaf(h, w2.x, a0[j]);
        a1[j] = fmaf(h, w2.y, a1[j]);
      }
    }
  }

  float2 g = *(const float2*)(gamma + c0);
  float2 b = *(const float2*)(beta + c0);
  for (int j = 0; j < 8; ++j) {
    int node = n0 + wv * 8 + j;
    float r0 = fmaxf(a0[j], 0.f);
    float r1 = fmaxf(a1[j], 0.f);
    float s = r0 + r1;
    for (int msk = 1; msk < 64; msk <<= 1) s += __shfl_xor(s, msk);
    float mean = s * (1.0f / 128.0f);
    float d0 = r0 - mean;
    float d1 = r1 - mean;
    float sq = d0 * d0 + d1 * d1;
    for (int msk = 1; msk < 64; msk <<= 1) sq += __shfl_xor(sq, msk);
    float rstd = rsqrtf(sq * (1.0f / 128.0f) + 1e-5f);
    if (node < N) {
      float2 o;
      o.x = d0 * rstd * g.x + b.x;
      o.y = d1 * rstd * g.y + b.y;
      *(float2*)(out + (size_t)node * HID + c0) = o;
    }
  }
}

extern "C" void kernel_launch(void* const* d_in, const int* in_sizes, int n_in,
                              void* d_out, int out_size, void* d_ws,
                              size_t ws_size, hipStream_t stream) {
  (void)n_in;
  (void)out_size;
  (void)ws_size;

  const int* edge_index = (const int*)d_in[0];
  const float* hX    = (const float*)d_in[1];
  const float* h_t   = (const float*)d_in[2];
  const float* Wq    = (const float*)d_in[3];
  const float* bq    = (const float*)d_in[4];
  const float* Wk    = (const float*)d_in[5];
  const float* bk    = (const float*)d_in[6];
  const float* Wv    = (const float*)d_in[7];
  const float* bv    = (const float*)d_in[8];
  const float* Wskip = (const float*)d_in[9];
  const float* bskip = (const float*)d_in[10];
  const float* Wup   = (const float*)d_in[11];
  const float* bup   = (const float*)d_in[12];
  const float* gamma = (const float*)d_in[13];
  const float* beta  = (const float*)d_in[14];

  const int E = in_sizes[0] / 2;
  const int N = in_sizes[1] / HID;
  const int* src_idx = edge_index;
  const int* dst_idx = edge_index + E;
  const int NB = (N + 255) / 256;
  const int NTILES = (N + 15) / 16;
  const int NTILES8 = ((NTILES + 7) / 8) * 8;

  // ---- workspace layout (~170 MB peak) ----
  char* w = (char*)d_ws;
  size_t off = 0;
  float* cvec = (float*)(w + off);
  off += 256 * 4;
  int* deg = (int*)(w + off);
  off += ((size_t)N * 4 + 255) / 256 * 256;
  int* row_ptr = (int*)(w + off);
  off += ((size_t)(N + 1) * 4 + 255) / 256 * 256;
  int* cursor = (int*)(w + off);
  off += ((size_t)N * 4 + 255) / 256 * 256;
  int* bsums = (int*)(w + off);
  off += ((size_t)NB * 4 + 255) / 256 * 256;
  int* boffs = (int*)(w + off);
  off += ((size_t)NB * 4 + 255) / 256 * 256;
  int* col = (int*)(w + off);
  off += ((size_t)E * 4 + 255) / 256 * 256;
  u16* hpack = (u16*)(w + off);
  off += ((size_t)NTILES8 * 2048 * 2 + 255) / 256 * 256;
  u16* Wp = (u16*)(w + off);     // [Wq|Wk|Wv|Wskip] 1664 cols, B-frag order
  off += ((size_t)128 * 1664 * 2 + 255) / 256 * 256;
  u16* bigA = (u16*)(w + off);   // q
  off += ((size_t)N * HC * 2 + 255) / 256 * 256;
  u16* bigB = (u16*)(w + off);   // k
  off += ((size_t)N * HC * 2 + 255) / 256 * 256;
  u16* bigC = (u16*)(w + off);   // v
  off += ((size_t)N * HC * 2 + 255) / 256 * 256;

  float* out = (float*)d_out;

  // ---- CSR build (parallel 3-phase scan) ----
  hipMemsetAsync(deg, 0, (size_t)N * 4, stream);
  hist_kernel<<<(E + 255) / 256, 256, 0, stream>>>(dst_idx, deg, E);
  blocksum_kernel<<<NB, 256, 0, stream>>>(deg, bsums, N);
  scanb_kernel<<<1, 256, 0, stream>>>(bsums, boffs, NB);
  scanfinal_kernel<<<NB, 256, 0, stream>>>(deg, boffs, row_ptr, cursor, N);
  scatter_kernel<<<(E + 255) / 256, 256, 0, stream>>>(src_idx, dst_idx, cursor,
                                                      col, E);

  // ---- packing for MFMA ----
  int totH = NTILES8 * 2048;
  packH_kernel<<<(totH + 255) / 256, 256, 0, stream>>>(hX, hpack, N, totH);
  packW4_kernel<<<(128 * 1664 + 255) / 256, 256, 0, stream>>>(
      Wq, Wk, Wv, Wskip, Wp, 128 * 1664);

  // ---- cvec ----
  cvec_kernel<<<1, 512, 0, stream>>>(h_t, Wup, bup, cvec);

  // ---- LDS-free MFMA projection: q->bigA, k->bigB, v->bigC, skip->d_out --
  mfma_proj_kernel<<<dim3(13, NTILES8 / 8), 256, 0, stream>>>(
      hpack, Wp, bq, bk, bv, bskip, bigA, bigB, bigC, out, N);

  // ---- fused score + online softmax + aggregate (pipelined) ----
  fused_attn_kernel<<<(N + 3) / 4, 256, 0, stream>>>(bigA, bigB, bigC, row_ptr,
                                                     col, out, N);

  // ---- update GEMM + relu + LayerNorm, in-place on d_out (tiled) ----
  ATTLayer_19396072308956_kernel<<<(N + UT - 1) / UT, 256, 0, stream>>>(
      out, Wup, cvec, gamma, beta, N);
}

// Round 4
// 390.049 us; speedup vs baseline: 1.1041x; 1.1041x over previous
//
#include <hip/hip_runtime.h>

typedef unsigned short u16;
typedef unsigned int   u32;

#define HID   128
#define HEADS 4
#define CH    128
#define HC    512
#define KVW   1024  // interleaved kv row width (u16): k cols 0-511, v cols 512-1023
#define UT    32    // nodes per block in the update GEMM

typedef __bf16 bf16x8v __attribute__((ext_vector_type(8)));
typedef float  f32x4v  __attribute__((ext_vector_type(4)));
union FragU { uint4 u; bf16x8v b; };

// bf16 pack/unpack for INTERNAL workspace tensors only (inputs/outputs f32)
static __device__ __forceinline__ float bf2f(u16 u) {
  union { u32 u; float f; } x;
  x.u = ((u32)u) << 16;
  return x.f;
}
static __device__ __forceinline__ u16 f2bf(float f) {
  union { float f; u32 u; } x;
  x.f = f;
  u32 r = x.u + 0x7fffu + ((x.u >> 16) & 1u);
  return (u16)(r >> 16);
}

static __device__ __forceinline__ void unpack8(uint4 raw, float* dst) {
  dst[0] = bf2f((u16)(raw.x & 0xffffu));
  dst[1] = bf2f((u16)(raw.x >> 16));
  dst[2] = bf2f((u16)(raw.y & 0xffffu));
  dst[3] = bf2f((u16)(raw.y >> 16));
  dst[4] = bf2f((u16)(raw.z & 0xffffu));
  dst[5] = bf2f((u16)(raw.z >> 16));
  dst[6] = bf2f((u16)(raw.w & 0xffffu));
  dst[7] = bf2f((u16)(raw.w >> 16));
}

// ---------------- CSR: histogram ----------------
__global__ void hist_kernel(const int* dst_idx, int* deg, int E) {
  int e = blockIdx.x * 256 + threadIdx.x;
  if (e < E) atomicAdd(&deg[dst_idx[e]], 1);
}

// ---------------- CSR scan phase 1: per-block sums ----------------
__global__ void blocksum_kernel(const int* deg, int* bsums, int n) {
  __shared__ int buf[256];
  int i = blockIdx.x * 256 + threadIdx.x;
  int v = 0;
  if (i < n) v = deg[i];
  buf[threadIdx.x] = v;
  __syncthreads();
  for (int off = 128; off > 0; off >>= 1) {
    if (threadIdx.x < off) buf[threadIdx.x] += buf[threadIdx.x + off];
    __syncthreads();
  }
  if (threadIdx.x == 0) bsums[blockIdx.x] = buf[0];
}

// ---------------- CSR scan phase 2: exclusive scan of block sums ------------
__global__ void scanb_kernel(const int* bsums, int* boffs, int nb) {
  __shared__ int buf[256];
  __shared__ int carry_s;
  int tid = threadIdx.x;
  if (tid == 0) carry_s = 0;
  __syncthreads();
  for (int base = 0; base < nb; base += 256) {
    int i = base + tid;
    int v = 0;
    if (i < nb) v = bsums[i];
    buf[tid] = v;
    __syncthreads();
    for (int off = 1; off < 256; off <<= 1) {
      int t = 0;
      if (tid >= off) t = buf[tid - off];
      __syncthreads();
      buf[tid] += t;
      __syncthreads();
    }
    int incl = buf[tid] + carry_s;
    if (i < nb) boffs[i] = incl - v;
    __syncthreads();
    if (tid == 255) carry_s = incl;
    __syncthreads();
  }
}

// ---------------- CSR scan phase 3: in-block scan + block offset ------------
__global__ void scanfinal_kernel(const int* deg, const int* boffs,
                                 int* row_ptr, int* cursor, int n) {
  __shared__ int buf[256];
  int tid = threadIdx.x;
  int i = blockIdx.x * 256 + tid;
  int v = 0;
  if (i < n) v = deg[i];
  buf[tid] = v;
  __syncthreads();
  for (int off = 1; off < 256; off <<= 1) {
    int t = 0;
    if (tid >= off) t = buf[tid - off];
    __syncthreads();
    buf[tid] += t;
    __syncthreads();
  }
  int incl = buf[tid] + boffs[blockIdx.x];
  if (i < n) {
    row_ptr[i + 1] = incl;
    cursor[i] = incl - v;
  }
  if (i == 0) row_ptr[0] = 0;
}

// ---------------- CSR: scatter ----------------
__global__ void scatter_kernel(const int* src_idx, const int* dst_idx,
                               int* cursor, int* col, int E) {
  int e = blockIdx.x * 256 + threadIdx.x;
  if (e < E) {
    int pos = atomicAdd(&cursor[dst_idx[e]], 1);
    col[pos] = src_idx[e];
  }
}

// ---- pack h_X into MFMA A-fragment order (bf16) ----
__global__ void packH_kernel(const float* __restrict__ hX,
                             u16* __restrict__ hpack, int N, int total) {
  int i = blockIdx.x * 256 + threadIdx.x;
  if (i >= total) return;
  int j = i & 7;
  int lane = (i >> 3) & 63;
  int kc = (i >> 9) & 3;
  int ntile = i >> 11;
  int node = ntile * 16 + (lane & 15);
  int k = kc * 32 + (lane >> 4) * 8 + j;
  float v = (node < N) ? hX[(size_t)node * HID + k] : 0.f;
  hpack[i] = f2bf(v);
}

// ---- pack [Wq|Wk|Wv|Wskip] (1664 cols) into B-fragment order (bf16) ----
__global__ void packW4_kernel(const float* __restrict__ Wq,
                              const float* __restrict__ Wk,
                              const float* __restrict__ Wv,
                              const float* __restrict__ Wsk,
                              u16* __restrict__ Wp, int total) {
  int i = blockIdx.x * 256 + threadIdx.x;
  if (i >= total) return;
  int j = i & 7;
  int lane = (i >> 3) & 63;
  int kc = (i >> 9) & 3;
  int ct = i >> 11;
  int n = ct * 16 + (lane & 15);
  int k = kc * 32 + (lane >> 4) * 8 + j;
  float w;
  if (n < 512) w = Wq[(size_t)k * HC + n];
  else if (n < 1024) w = Wk[(size_t)k * HC + (n - 512)];
  else if (n < 1536) w = Wv[(size_t)k * HC + (n - 1024)];
  else w = Wsk[(size_t)k * HID + (n - 1536)];
  Wp[i] = f2bf(w);
}

// ---- MFMA projection: LDS-free, B-in-registers, M-chunked ----
// k and v now land INTERLEAVED in one kv buffer: row = node*1024 u16,
// k in cols 0-511, v in cols 512-1023. For n in [512,1536) both map to
// kvb with stride 1024 and col n-512 (v's +512 offset is absorbed).
__global__ __launch_bounds__(256) void mfma_proj_kernel(
    const u16* __restrict__ hpack, const u16* __restrict__ Wp,
    const float* __restrict__ bq, const float* __restrict__ bk,
    const float* __restrict__ bv, const float* __restrict__ bsk,
    u16* __restrict__ qb, u16* __restrict__ kvb,
    float* __restrict__ skipf, int N) {
  int t = threadIdx.x;
  int wv = t >> 6;
  int L = t & 63;
  int bx = blockIdx.x;        // 0..12 : block covers 8 col-tiles, wave 2
  int my0 = blockIdx.y * 8;   // 8 m-tiles (128 nodes) per block

  // ---- B fragments: 2 col-tiles x 4 kc, loaded once (L2-resident) ----
  FragU Bf[2][4];
  const u16* wb0 = Wp + (size_t)(bx * 8 + wv * 2) * 2048;
#pragma unroll
  for (int cc = 0; cc < 2; ++cc)
#pragma unroll
    for (int kc = 0; kc < 4; ++kc)
      Bf[cc][kc].u = *(const uint4*)(wb0 + cc * 2048 + kc * 512 + L * 8);

  // ---- per-cc output routing (wave-uniform) + per-lane bias ----
  int colq = L & 15;
  int quad = L >> 4;
  u16* outB_[2];
  int stride_[2];
  float bval[2];
  int nl_[2];
  int isF32_[2];
#pragma unroll
  for (int cc = 0; cc < 2; ++cc) {
    int n = (bx * 8 + wv * 2 + cc) * 16 + colq;
    const float* bias;
    if (n < 512) {
      outB_[cc] = qb; bias = bq; nl_[cc] = n; stride_[cc] = HC; isF32_[cc] = 0;
    } else if (n < 1024) {
      outB_[cc] = kvb; bias = bk; nl_[cc] = n - 512; stride_[cc] = KVW;
      isF32_[cc] = 0;
    } else if (n < 1536) {
      // v: col 512 + (n-1024) = n - 512 in the interleaved row
      outB_[cc] = kvb; bias = bv; nl_[cc] = n - 512; stride_[cc] = KVW;
      isF32_[cc] = 0;
    } else {
      outB_[cc] = (u16*)skipf; bias = bsk; nl_[cc] = n - 1536; stride_[cc] = 0;
      isF32_[cc] = 1;
    }
    bval[cc] = bias[nl_[cc]];
  }

  const u16* ha = hpack + (size_t)my0 * 2048;

  for (int mt = 0; mt < 8; mt += 2) {
    // issue all 8 A-fragment loads before any MFMA
    FragU a0[4], a1[4];
#pragma unroll
    for (int kc = 0; kc < 4; ++kc) {
      a0[kc].u = *(const uint4*)(ha + (size_t)mt * 2048 + kc * 512 + L * 8);
      a1[kc].u =
          *(const uint4*)(ha + (size_t)(mt + 1) * 2048 + kc * 512 + L * 8);
    }

    f32x4v ac00 = (f32x4v){0.f, 0.f, 0.f, 0.f};
    f32x4v ac01 = (f32x4v){0.f, 0.f, 0.f, 0.f};
    f32x4v ac10 = (f32x4v){0.f, 0.f, 0.f, 0.f};
    f32x4v ac11 = (f32x4v){0.f, 0.f, 0.f, 0.f};
#pragma unroll
    for (int kc = 0; kc < 4; ++kc) {
      ac00 = __builtin_amdgcn_mfma_f32_16x16x32_bf16(a0[kc].b, Bf[0][kc].b,
                                                     ac00, 0, 0, 0);
      ac01 = __builtin_amdgcn_mfma_f32_16x16x32_bf16(a0[kc].b, Bf[1][kc].b,
                                                     ac01, 0, 0, 0);
      ac10 = __builtin_amdgcn_mfma_f32_16x16x32_bf16(a1[kc].b, Bf[0][kc].b,
                                                     ac10, 0, 0, 0);
      ac11 = __builtin_amdgcn_mfma_f32_16x16x32_bf16(a1[kc].b, Bf[1][kc].b,
                                                     ac11, 0, 0, 0);
    }

    // epilogue: bias + convert + store (wave-uniform branch per cc)
#pragma unroll
    for (int half = 0; half < 2; ++half) {
      int nodeBase = (my0 + mt + half) * 16 + quad * 4;
#pragma unroll
      for (int cc = 0; cc < 2; ++cc) {
        const f32x4v& a =
            half ? (cc ? ac11 : ac10) : (cc ? ac01 : ac00);
        if (isF32_[cc]) {
#pragma unroll
          for (int rg = 0; rg < 4; ++rg) {
            int node = nodeBase + rg;
            if (node < N)
              skipf[(size_t)node * HID + nl_[cc]] = a[rg] + bval[cc];
          }
        } else {
          u16* ob = outB_[cc];
          int st = stride_[cc];
#pragma unroll
          for (int rg = 0; rg < 4; ++rg) {
            int node = nodeBase + rg;
            if (node < N)
              ob[(size_t)node * st + nl_[cc]] = f2bf(a[rg] + bval[cc]);
          }
        }
      }
    }
  }
}

// ---- FUSED per-node attention: 4-edge unroll (8 gathers in flight) ----
// Round-2 structure verbatim (no explicit prefetch: round-3's double-buffer
// spilled to scratch, WRITE 25->180MB, 121->157us). Single change: k and v
// come from ONE interleaved row (2KB contiguous per source node) instead of
// two 1KB rows ~51MB apart -> half the distinct DRAM/L3 regions per group.
__global__ void fused_attn_kernel(const u16* __restrict__ qb,
                                  const u16* __restrict__ kvb,
                                  const int* __restrict__ row_ptr,
                                  const int* __restrict__ col_src,
                                  float* out, int N) {
  int node = blockIdx.x * 4 + (threadIdx.x >> 6);
  if (node >= N) return;
  int lane = threadIdx.x & 63;
  int head = lane >> 4;
  int r = lane & 15;
  int foff = head * CH + r * 8;
  const float sscale = 0.08838834764831845f;  // 1/sqrt(128)

  float qf[8];
  unpack8(*(const uint4*)(qb + (size_t)node * HC + foff), qf);

  float m = -3.402823466e38f;
  float l = 0.f;
  float acc[8];
  for (int j = 0; j < 8; ++j) acc[j] = 0.f;

  int e0 = row_ptr[node];
  int e1 = row_ptr[node + 1];
  int e = e0;

  for (; e + 4 <= e1; e += 4) {
    int s0 = col_src[e];
    int s1 = col_src[e + 1];
    int s2 = col_src[e + 2];
    int s3 = col_src[e + 3];
    const u16* r0p = kvb + (size_t)s0 * KVW + foff;
    const u16* r1p = kvb + (size_t)s1 * KVW + foff;
    const u16* r2p = kvb + (size_t)s2 * KVW + foff;
    const u16* r3p = kvb + (size_t)s3 * KVW + foff;
    // issue all 8 gathers before any dependent use (k and v 1KB apart
    // within the same 2KB row)
    uint4 k0 = *(const uint4*)(r0p);
    uint4 k1 = *(const uint4*)(r1p);
    uint4 k2 = *(const uint4*)(r2p);
    uint4 k3 = *(const uint4*)(r3p);
    uint4 v0 = *(const uint4*)(r0p + 512);
    uint4 v1 = *(const uint4*)(r1p + 512);
    uint4 v2 = *(const uint4*)(r2p + 512);
    uint4 v3 = *(const uint4*)(r3p + 512);

    float kf0[8], kf1[8], kf2[8], kf3[8];
    unpack8(k0, kf0);
    unpack8(k1, kf1);
    unpack8(k2, kf2);
    unpack8(k3, kf3);
    float p0 = 0.f, p1 = 0.f, p2 = 0.f, p3 = 0.f;
    for (int j = 0; j < 8; ++j) {
      p0 = fmaf(kf0[j], qf[j], p0);
      p1 = fmaf(kf1[j], qf[j], p1);
      p2 = fmaf(kf2[j], qf[j], p2);
      p3 = fmaf(kf3[j], qf[j], p3);
    }
    p0 += __shfl_xor(p0, 1);
    p1 += __shfl_xor(p1, 1);
    p2 += __shfl_xor(p2, 1);
    p3 += __shfl_xor(p3, 1);
    p0 += __shfl_xor(p0, 2);
    p1 += __shfl_xor(p1, 2);
    p2 += __shfl_xor(p2, 2);
    p3 += __shfl_xor(p3, 2);
    p0 += __shfl_xor(p0, 4);
    p1 += __shfl_xor(p1, 4);
    p2 += __shfl_xor(p2, 4);
    p3 += __shfl_xor(p3, 4);
    p0 += __shfl_xor(p0, 8);
    p1 += __shfl_xor(p1, 8);
    p2 += __shfl_xor(p2, 8);
    p3 += __shfl_xor(p3, 8);
    float sc0 = p0 * sscale;
    float sc1 = p1 * sscale;
    float sc2 = p2 * sscale;
    float sc3 = p3 * sscale;
    float mnew = fmaxf(fmaxf(m, fmaxf(sc0, sc1)), fmaxf(sc2, sc3));
    float so = __expf(m - mnew);
    float pe0 = __expf(sc0 - mnew);
    float pe1 = __expf(sc1 - mnew);
    float pe2 = __expf(sc2 - mnew);
    float pe3 = __expf(sc3 - mnew);
    l = l * so + (pe0 + pe1) + (pe2 + pe3);
    float vf0[8], vf1[8], vf2[8], vf3[8];
    unpack8(v0, vf0);
    unpack8(v1, vf1);
    unpack8(v2, vf2);
    unpack8(v3, vf3);
    for (int j = 0; j < 8; ++j) {
      float add = fmaf(pe0, vf0[j],
                       fmaf(pe1, vf1[j], fmaf(pe2, vf2[j], pe3 * vf3[j])));
      acc[j] = fmaf(acc[j], so, add);
    }
    m = mnew;
  }

  for (; e < e1; ++e) {  // tail: 0-3 edges
    int s0 = col_src[e];
    const u16* r0p = kvb + (size_t)s0 * KVW + foff;
    uint4 k0 = *(const uint4*)(r0p);
    uint4 v0 = *(const uint4*)(r0p + 512);
    float kf0[8];
    unpack8(k0, kf0);
    float p0 = 0.f;
    for (int j = 0; j < 8; ++j) p0 = fmaf(kf0[j], qf[j], p0);
    p0 += __shfl_xor(p0, 1);
    p0 += __shfl_xor(p0, 2);
    p0 += __shfl_xor(p0, 4);
    p0 += __shfl_xor(p0, 8);
    float sc0 = p0 * sscale;
    float mnew = fmaxf(m, sc0);
    float so = __expf(m - mnew);
    float pe0 = __expf(sc0 - mnew);
    l = l * so + pe0;
    float vf0[8];
    unpack8(v0, vf0);
    for (int j = 0; j < 8; ++j) acc[j] = fmaf(acc[j], so, pe0 * vf0[j]);
    m = mnew;
  }

  float inv = 0.f;
  if (l > 0.f) inv = 1.0f / l;
  float val[8];
  for (int j = 0; j < 8; ++j) {
    float x = acc[j] * inv;
    x += __shfl_xor(x, 16);
    x += __shfl_xor(x, 32);
    val[j] = x * 0.25f;  // mean over 4 heads
  }

  if (head == 0) {
    float* p = out + (size_t)node * HID + r * 8;
    float4 a = *(const float4*)(p);
    float4 b = *(const float4*)(p + 4);
    a.x += val[0]; a.y += val[1]; a.z += val[2]; a.w += val[3];
    b.x += val[4]; b.y += val[5]; b.z += val[6]; b.w += val[7];
    *(float4*)(p) = a;
    *(float4*)(p + 4) = b;
  }
}

// ---------------- cvec = h_t @ Wup[128:256] + bup (all f32) ----------------
// parallelized: 4 k-chunks x 128 cols (one block, 512 threads)
__global__ void cvec_kernel(const float* h_t, const float* Wup,
                            const float* bup, float* cvec) {
  __shared__ float part[4][128];
  int c = threadIdx.x & 127;
  int kc = threadIdx.x >> 7;
  float acc = 0.f;
  for (int k = kc * 32; k < kc * 32 + 32; ++k)
    acc = fmaf(h_t[k], Wup[(size_t)(128 + k) * 128 + c], acc);
  part[kc][c] = acc;
  __syncthreads();
  if (kc == 0)
    cvec[c] = part[0][c] + part[1][c] + part[2][c] + part[3][c] + bup[c];
}

// ------- update GEMM + relu + LayerNorm, in-place on d_out (f32) -------
__global__ __launch_bounds__(256) void ATTLayer_19396072308956_kernel(
    float* out, const float* __restrict__ Wup, const float* __restrict__ cvec,
    const float* __restrict__ gamma, const float* __restrict__ beta, int N) {
  __shared__ float Wl[64 * 128];
  __shared__ float Hl[UT * 128];
  int t = threadIdx.x;
  int n0 = blockIdx.x * UT;

  for (int i = t * 4; i < UT * 128; i += 1024) {
    int node = n0 + (i >> 7);
    float4 v;
    if (node < N) {
      v = *(const float4*)(out + (size_t)node * HID + (i & 127));
    } else {
      v.x = 0.f; v.y = 0.f; v.z = 0.f; v.w = 0.f;
    }
    *(float4*)(Hl + i) = v;
  }

  int wv = t >> 6;
  int r = t & 63;
  int c0 = 2 * r;
  float2 cv = *(const float2*)(cvec + c0);
  float a0[8];
  float a1[8];
  for (int j = 0; j < 8; ++j) {
    a0[j] = cv.x;
    a1[j] = cv.y;
  }

  for (int ph = 0; ph < 2; ++ph) {
    __syncthreads();
    for (int i = t * 4; i < 64 * 128; i += 1024) {
      *(float4*)(Wl + i) = *(const float4*)(Wup + (size_t)ph * 64 * 128 + i);
    }
    __syncthreads();
    const float* hbase = Hl + (wv * 8) * 128 + ph * 64;
#pragma unroll 8
    for (int k = 0; k < 64; ++k) {
      float2 w2 = *(const float2*)(Wl + k * 128 + c0);
      for (int j = 0; j < 8; ++j) {
        float h = hbase[j * 128 + k];
        a0[j] = fmaf(h, w2.x, a0[j]);
        a1[j] = fmaf(h, w2.y, a1[j]);
      }
    }
  }

  float2 g = *(const float2*)(gamma + c0);
  float2 b = *(const float2*)(beta + c0);
  for (int j = 0; j < 8; ++j) {
    int node = n0 + wv * 8 + j;
    float r0 = fmaxf(a0[j], 0.f);
    float r1 = fmaxf(a1[j], 0.f);
    float s = r0 + r1;
    for (int msk = 1; msk < 64; msk <<= 1) s += __shfl_xor(s, msk);
    float mean = s * (1.0f / 128.0f);
    float d0 = r0 - mean;
    float d1 = r1 - mean;
    float sq = d0 * d0 + d1 * d1;
    for (int msk = 1; msk < 64; msk <<= 1) sq += __shfl_xor(sq, msk);
    float rstd = rsqrtf(sq * (1.0f / 128.0f) + 1e-5f);
    if (node < N) {
      float2 o;
      o.x = d0 * rstd * g.x + b.x;
      o.y = d1 * rstd * g.y + b.y;
      *(float2*)(out + (size_t)node * HID + c0) = o;
    }
  }
}

extern "C" void kernel_launch(void* const* d_in, const int* in_sizes, int n_in,
                              void* d_out, int out_size, void* d_ws,
                              size_t ws_size, hipStream_t stream) {
  (void)n_in;
  (void)out_size;
  (void)ws_size;

  const int* edge_index = (const int*)d_in[0];
  const float* hX    = (const float*)d_in[1];
  const float* h_t   = (const float*)d_in[2];
  const float* Wq    = (const float*)d_in[3];
  const float* bq    = (const float*)d_in[4];
  const float* Wk    = (const float*)d_in[5];
  const float* bk    = (const float*)d_in[6];
  const float* Wv    = (const float*)d_in[7];
  const float* bv    = (const float*)d_in[8];
  const float* Wskip = (const float*)d_in[9];
  const float* bskip = (const float*)d_in[10];
  const float* Wup   = (const float*)d_in[11];
  const float* bup   = (const float*)d_in[12];
  const float* gamma = (const float*)d_in[13];
  const float* beta  = (const float*)d_in[14];

  const int E = in_sizes[0] / 2;
  const int N = in_sizes[1] / HID;
  const int* src_idx = edge_index;
  const int* dst_idx = edge_index + E;
  const int NB = (N + 255) / 256;
  const int NTILES = (N + 15) / 16;
  const int NTILES8 = ((NTILES + 7) / 8) * 8;

  // ---- workspace layout (~170 MB peak) ----
  char* w = (char*)d_ws;
  size_t off = 0;
  float* cvec = (float*)(w + off);
  off += 256 * 4;
  int* deg = (int*)(w + off);
  off += ((size_t)N * 4 + 255) / 256 * 256;
  int* row_ptr = (int*)(w + off);
  off += ((size_t)(N + 1) * 4 + 255) / 256 * 256;
  int* cursor = (int*)(w + off);
  off += ((size_t)N * 4 + 255) / 256 * 256;
  int* bsums = (int*)(w + off);
  off += ((size_t)NB * 4 + 255) / 256 * 256;
  int* boffs = (int*)(w + off);
  off += ((size_t)NB * 4 + 255) / 256 * 256;
  int* col = (int*)(w + off);
  off += ((size_t)E * 4 + 255) / 256 * 256;
  u16* hpack = (u16*)(w + off);
  off += ((size_t)NTILES8 * 2048 * 2 + 255) / 256 * 256;
  u16* Wp = (u16*)(w + off);     // [Wq|Wk|Wv|Wskip] 1664 cols, B-frag order
  off += ((size_t)128 * 1664 * 2 + 255) / 256 * 256;
  u16* bigA = (u16*)(w + off);   // q [N][512]
  off += ((size_t)N * HC * 2 + 255) / 256 * 256;
  u16* bigKV = (u16*)(w + off);  // interleaved k|v [N][1024]
  off += ((size_t)N * KVW * 2 + 255) / 256 * 256;

  float* out = (float*)d_out;

  // ---- CSR build (parallel 3-phase scan) ----
  hipMemsetAsync(deg, 0, (size_t)N * 4, stream);
  hist_kernel<<<(E + 255) / 256, 256, 0, stream>>>(dst_idx, deg, E);
  blocksum_kernel<<<NB, 256, 0, stream>>>(deg, bsums, N);
  scanb_kernel<<<1, 256, 0, stream>>>(bsums, boffs, NB);
  scanfinal_kernel<<<NB, 256, 0, stream>>>(deg, boffs, row_ptr, cursor, N);
  scatter_kernel<<<(E + 255) / 256, 256, 0, stream>>>(src_idx, dst_idx, cursor,
                                                      col, E);

  // ---- packing for MFMA ----
  int totH = NTILES8 * 2048;
  packH_kernel<<<(totH + 255) / 256, 256, 0, stream>>>(hX, hpack, N, totH);
  packW4_kernel<<<(128 * 1664 + 255) / 256, 256, 0, stream>>>(
      Wq, Wk, Wv, Wskip, Wp, 128 * 1664);

  // ---- cvec ----
  cvec_kernel<<<1, 512, 0, stream>>>(h_t, Wup, bup, cvec);

  // ---- LDS-free MFMA projection: q->bigA, k/v->bigKV, skip->d_out ----
  mfma_proj_kernel<<<dim3(13, NTILES8 / 8), 256, 0, stream>>>(
      hpack, Wp, bq, bk, bv, bskip, bigA, bigKV, out, N);

  // ---- fused score + online softmax + aggregate (4-edge unroll) ----
  fused_attn_kernel<<<(N + 3) / 4, 256, 0, stream>>>(bigA, bigKV, row_ptr,
                                                     col, out, N);

  // ---- update GEMM + relu + LayerNorm, in-place on d_out (tiled) ----
  ATTLayer_19396072308956_kernel<<<(N + UT - 1) / UT, 256, 0, stream>>>(
      out, Wup, cvec, gamma, beta, N);
}